// Round 4
// baseline (442.173 us; speedup 1.0000x reference)
//
#include <hip/hip_runtime.h>
#include <hip/hip_fp16.h>
#include <math.h>

typedef _Float16 f16;
typedef _Float16 f16x8 __attribute__((ext_vector_type(8)));
typedef float f32x4 __attribute__((ext_vector_type(4)));
typedef unsigned char u8;

#define HDIM 256
#define TST 128
#define OUTD 10
#define S2LE 2.8853900817779268f   // 2*log2(e)

// 8 waves/block (512 thr), wave w owns hidden rows [w*32, w*32+32), 16 batch
// cols/block. wf[2][8]=64 VGPR; B-frags JIT from LDS (4-reg rotation);
// __launch_bounds__(512,4) forces <=128 VGPR -> 4 waves/SIMD, 2 blocks/CU.
// Algebra (R3-verified): y = rs*(W_g@tv) - rs*mu*RSg + D1[xv], frag = f16(tv).
// C-init = dd*(1/rs) - mu*RSg so dd regs die before the MFMA cluster.
__global__ __launch_bounds__(512, 4) void rnn_kernel(
    const float* __restrict__ x,
    const float* __restrict__ embed_w,
    const float* __restrict__ embed_b,
    const float* __restrict__ update_w,
    const float* __restrict__ update_b,
    const float* __restrict__ gamma,
    const float* __restrict__ beta,
    const float* __restrict__ out_w,
    const float* __restrict__ out_b,
    float* __restrict__ out)
{
  __shared__ __align__(16) char  sFR[2][8][64][16];  // frag dbuf 16K; overlays: T0 (init), sOut (post)
  __shared__ __align__(16) float sD1[10 * 260];      // 10.4K; overlay post: sOW (8K)
  __shared__ __align__(16) float sBW[HDIM];
  __shared__ __align__(16) float sRSg[HDIM];
  __shared__ __align__(16) float sST[2][16][20];     // [p][ml][w]=s1, [8+w]=s2; stride 20 -> conflict-free
  __shared__ float sOB[16];
  __shared__ u8    sXb[TST][16];

  const int tid = threadIdx.x;
  const int w   = tid >> 6;        // 0..7
  const int l   = tid & 63;
  const int q   = l >> 4;
  const int ml  = l & 15;
  const int base = blockIdx.x * 16;
  const int nb  = w * 32 + q * 4;  // n = nb + nt*16 + r

  float* T0 = (float*)&sFR[0][0][0][0];   // [256][10] init-only overlay

  // ---------- P1 ----------
  if (tid < 256) {
    float ew = embed_w[tid], eb = embed_b[tid];
    #pragma unroll
    for (int xv = 0; xv < 10; xv++)
      T0[tid * 10 + xv] = tanhf((float)xv * ew + eb);
  }
  for (int idx = tid; idx < 16 * TST; idx += 512) {
    int m = idx >> 7, tt = idx & 127;
    sXb[tt][m] = (u8)(int)x[(size_t)(base + m) * TST + tt];
  }
  if (tid < 16) {
    float v = 0.f;
    if (tid < OUTD) {
      v = out_b[tid];
      const float* orow = out_w + tid * HDIM;
      for (int k = 0; k < HDIM; k += 4) {
        float4 wv = *(const float4*)(orow + k);
        float4 bv = *(const float4*)(beta + k);
        v = fmaf(wv.x, bv.x, fmaf(wv.y, bv.y, fmaf(wv.z, bv.z, fmaf(wv.w, bv.w, v))));
      }
    }
    sOB[tid] = v;
  }
  __syncthreads();

  // ---------- P2: per-n tables (threads 0..255) ----------
  if (tid < 256) {
    const int n = tid;
    const float* wrow = update_w + n * HDIM;
    float ty[10];
    #pragma unroll
    for (int xv = 0; xv < 10; xv++) ty[xv] = 0.f;
    float bw = 0.f, rsg = 0.f;
    for (int k = 0; k < HDIM; k += 4) {
      float4 wv4 = *(const float4*)(wrow + k);
      float4 b4  = *(const float4*)(beta + k);
      float4 g4  = *(const float4*)(gamma + k);
      bw  = fmaf(wv4.x, b4.x, fmaf(wv4.y, b4.y, fmaf(wv4.z, b4.z, fmaf(wv4.w, b4.w, bw))));
      rsg = fmaf(wv4.x, S2LE * g4.x, fmaf(wv4.y, S2LE * g4.y,
            fmaf(wv4.z, S2LE * g4.z, fmaf(wv4.w, S2LE * g4.w, rsg))));
      #pragma unroll
      for (int kk = 0; kk < 4; kk++) {
        float wv = ((const float*)&wv4)[kk];
        const float* t0r = T0 + (k + kk) * 10;
        #pragma unroll
        for (int xv = 0; xv < 10; xv++) ty[xv] = fmaf(wv, t0r[xv], ty[xv]);
      }
    }
    float ubn = update_b[n];
    sBW[n]  = S2LE * bw;
    sRSg[n] = rsg;
    #pragma unroll
    for (int xv = 0; xv < 10; xv++)
      sD1[xv * 260 + n] = S2LE * (ty[xv] + ubn + bw);
  }
  __syncthreads();

  // ---------- W_g fragments (64 VGPR) + RSg ----------
  f16x8 wf[2][8];
  #pragma unroll
  for (int c = 0; c < 8; c++) {
    const int k0 = c * 32 + q * 4;
    float4 g0 = *(const float4*)(gamma + k0);
    float4 g1 = *(const float4*)(gamma + k0 + 16);
    #pragma unroll
    for (int nt = 0; nt < 2; nt++) {
      const float* wrow = update_w + (w * 32 + nt * 16 + ml) * HDIM;
      float4 a0 = *(const float4*)(wrow + k0);
      float4 a1 = *(const float4*)(wrow + k0 + 16);
      f16x8 f;
      f[0]=(f16)(S2LE*g0.x*a0.x); f[1]=(f16)(S2LE*g0.y*a0.y);
      f[2]=(f16)(S2LE*g0.z*a0.z); f[3]=(f16)(S2LE*g0.w*a0.w);
      f[4]=(f16)(S2LE*g1.x*a1.x); f[5]=(f16)(S2LE*g1.y*a1.y);
      f[6]=(f16)(S2LE*g1.z*a1.z); f[7]=(f16)(S2LE*g1.w*a1.w);
      wf[nt][c] = f;
    }
  }
  f32x4 rsgr[2];
  rsgr[0] = *(const f32x4*)(sRSg + nb);
  rsgr[1] = *(const f32x4*)(sRSg + nb + 16);

  // ---------- prologue t=0: y0 = D1[xv0] - BW ----------
  f32x4 tv0, tv1;
  {
    const int xv0 = (int)sXb[0][ml];
    const float* dp = sD1 + xv0 * 260 + nb;
    f32x4 dd0 = *(const f32x4*)(dp);
    f32x4 dd1 = *(const f32x4*)(dp + 16);
    f32x4 bw0 = *(const f32x4*)(sBW + nb);
    f32x4 bw1 = *(const f32x4*)(sBW + nb + 16);
    float p1 = 0.f, p2 = 0.f;
    #pragma unroll
    for (int r = 0; r < 4; r++) {
      float y = dd0[r] - bw0[r];
      float e = __builtin_amdgcn_exp2f(y);
      float t = fmaf(-2.f, __builtin_amdgcn_rcpf(e + 1.f), 1.f);
      tv0[r] = t; p1 += t; p2 = fmaf(t, t, p2);
    }
    #pragma unroll
    for (int r = 0; r < 4; r++) {
      float y = dd1[r] - bw1[r];
      float e = __builtin_amdgcn_exp2f(y);
      float t = fmaf(-2.f, __builtin_amdgcn_rcpf(e + 1.f), 1.f);
      tv1[r] = t; p1 += t; p2 = fmaf(t, t, p2);
    }
    p1 += __shfl_xor(p1, 16, 64); p2 += __shfl_xor(p2, 16, 64);
    p1 += __shfl_xor(p1, 32, 64); p2 += __shfl_xor(p2, 32, 64);
    if (l < 16) { sST[0][ml][w] = p1; sST[0][ml][8 + w] = p2; }
    f16x8 af;
    #pragma unroll
    for (int j = 0; j < 4; j++) af[j] = (f16)tv0[j];
    #pragma unroll
    for (int j = 0; j < 4; j++) af[4 + j] = (f16)tv1[j];
    *(f16x8*)(&sFR[0][w][l][0]) = af;
    __syncthreads();
  }

  // ---------- main loop: 1 barrier/step ----------
  #pragma unroll 1
  for (int t = 1; t < TST; t++) {
    const int p = t & 1, pp = p ^ 1;
    // stats of step t-1
    const float* st = &sST[pp][ml][0];
    f32x4 a0 = *(const f32x4*)(st);
    f32x4 a1 = *(const f32x4*)(st + 4);
    f32x4 b0 = *(const f32x4*)(st + 8);
    f32x4 b1 = *(const f32x4*)(st + 12);
    f32x4 sv = a0 + a1, qv = b0 + b1;
    float S1 = (sv[0] + sv[1]) + (sv[2] + sv[3]);
    float S2 = (qv[0] + qv[1]) + (qv[2] + qv[3]);
    float mu = S1 * (1.f / 256.f);
    float rs = __frsqrt_rn(fmaf(S2, 1.f / 256.f, -mu * mu) + 1e-5f);
    float inv = __builtin_amdgcn_rcpf(rs);      // 1/rs
    // C-init = dd/rs - mu*RSg  (dd regs die here)
    const int xv = (int)sXb[t][ml];
    const float* dp = sD1 + xv * 260 + nb;
    f32x4 dd0 = *(const f32x4*)(dp);
    f32x4 dd1 = *(const f32x4*)(dp + 16);
    f32x4 acc0, acc1;
    #pragma unroll
    for (int r = 0; r < 4; r++) {
      acc0[r] = fmaf(dd0[r], inv, -mu * rsgr[0][r]);
      acc1[r] = fmaf(dd1[r], inv, -mu * rsgr[1][r]);
    }
    // MFMA with JIT B-frags (4-reg rotation, prefetch depth 2)
    const char* fb = &sFR[pp][0][l][0];
    f16x8 rg[4];
    rg[0] = *(const f16x8*)(fb);
    rg[1] = *(const f16x8*)(fb + 1024);
    __builtin_amdgcn_s_setprio(1);
    #pragma unroll
    for (int c = 0; c < 8; c++) {
      if (c < 6) rg[(c + 2) & 3] = *(const f16x8*)(fb + (c + 2) * 1024);
      acc0 = __builtin_amdgcn_mfma_f32_16x16x32_f16(wf[0][c], rg[c & 3], acc0, 0, 0, 0);
      acc1 = __builtin_amdgcn_mfma_f32_16x16x32_f16(wf[1][c], rg[c & 3], acc1, 0, 0, 0);
    }
    __builtin_amdgcn_s_setprio(0);
    // y = rs*acc ; tanh; stats
    float p1 = 0.f, p2 = 0.f;
    #pragma unroll
    for (int r = 0; r < 4; r++) {
      float y = rs * acc0[r];
      float e = __builtin_amdgcn_exp2f(y);
      float tvv = fmaf(-2.f, __builtin_amdgcn_rcpf(e + 1.f), 1.f);
      tv0[r] = tvv; p1 += tvv; p2 = fmaf(tvv, tvv, p2);
    }
    #pragma unroll
    for (int r = 0; r < 4; r++) {
      float y = rs * acc1[r];
      float e = __builtin_amdgcn_exp2f(y);
      float tvv = fmaf(-2.f, __builtin_amdgcn_rcpf(e + 1.f), 1.f);
      tv1[r] = tvv; p1 += tvv; p2 = fmaf(tvv, tvv, p2);
    }
    p1 += __shfl_xor(p1, 16, 64); p2 += __shfl_xor(p2, 16, 64);
    p1 += __shfl_xor(p1, 32, 64); p2 += __shfl_xor(p2, 32, 64);
    if (l < 16) { sST[p][ml][w] = p1; sST[p][ml][8 + w] = p2; }
    f16x8 af;
    #pragma unroll
    for (int j = 0; j < 4; j++) af[j] = (f16)tv0[j];
    #pragma unroll
    for (int j = 0; j < 4; j++) af[4 + j] = (f16)tv1[j];
    *(f16x8*)(&sFR[p][w][l][0]) = af;
    __syncthreads();
  }

  // ---------- epilogue ----------
  {
    // stats of t=127 live in sST[1]
    const float* st = &sST[1][ml][0];
    f32x4 a0 = *(const f32x4*)(st);
    f32x4 a1 = *(const f32x4*)(st + 4);
    f32x4 b0 = *(const f32x4*)(st + 8);
    f32x4 b1 = *(const f32x4*)(st + 12);
    f32x4 sv = a0 + a1, qv = b0 + b1;
    float S1 = (sv[0] + sv[1]) + (sv[2] + sv[3]);
    float S2 = (qv[0] + qv[1]) + (qv[2] + qv[3]);
    float mu = S1 * (1.f / 256.f);
    float rs = __frsqrt_rn(fmaf(S2, 1.f / 256.f, -mu * mu) + 1e-5f);
    float nrsmu = -rs * mu;
    f16x8 af;
    #pragma unroll
    for (int j = 0; j < 4; j++) af[j] = (f16)fmaf(rs, tv0[j], nrsmu);
    #pragma unroll
    for (int j = 0; j < 4; j++) af[4 + j] = (f16)fmaf(rs, tv1[j], nrsmu);

    // build sOW (gamma-folded out_w frags) in sD1's space
    f16* sOW = (f16*)sD1;
    {
      int c = tid >> 6, l2 = tid & 63, q2 = l2 >> 4, o = l2 & 15;
      int k0 = c * 32 + q2 * 4;
      f16x8 f;
      #pragma unroll
      for (int j = 0; j < 8; j++) f[j] = (f16)0.f;
      if (o < OUTD) {
        const float* orow = out_w + o * HDIM;
        float4 a0g = *(const float4*)(orow + k0);
        float4 a1g = *(const float4*)(orow + k0 + 16);
        float4 g0 = *(const float4*)(gamma + k0);
        float4 g1 = *(const float4*)(gamma + k0 + 16);
        f[0]=(f16)(g0.x*a0g.x); f[1]=(f16)(g0.y*a0g.y); f[2]=(f16)(g0.z*a0g.z); f[3]=(f16)(g0.w*a0g.w);
        f[4]=(f16)(g1.x*a1g.x); f[5]=(f16)(g1.y*a1g.y); f[6]=(f16)(g1.z*a1g.z); f[7]=(f16)(g1.w*a1g.w);
      }
      *(f16x8*)(sOW + (size_t)tid * 8) = f;
    }
    __syncthreads();
    f32x4 aO = {0.f, 0.f, 0.f, 0.f};
    {
      f16x8 of = *(const f16x8*)(sOW + ((size_t)w * 64 + l) * 8);
      aO = __builtin_amdgcn_mfma_f32_16x16x32_f16(of, af, aO, 0, 0, 0);
    }
    float* sOut = (float*)&sFR[0][0][0][0];   // [8][16][16]
    #pragma unroll
    for (int r = 0; r < 4; r++)
      sOut[(w * 16 + ml) * 16 + q * 4 + r] = aO[r];
    __syncthreads();
    if (tid < 16 * OUTD) {
      int m = tid / OUTD, o = tid % OUTD;
      float s = 0.f;
      #pragma unroll
      for (int ww = 0; ww < 8; ww++) s += sOut[(ww * 16 + m) * 16 + o];
      out[(size_t)(base + m) * OUTD + o] = s + sOB[o];
    }
  }
}

extern "C" void kernel_launch(void* const* d_in, const int* in_sizes, int n_in,
                              void* d_out, int out_size, void* d_ws, size_t ws_size,
                              hipStream_t stream) {
  const float* x   = (const float*)d_in[0];
  const float* ew  = (const float*)d_in[1];
  const float* eb  = (const float*)d_in[2];
  const float* uw  = (const float*)d_in[3];
  const float* ub  = (const float*)d_in[4];
  const float* g   = (const float*)d_in[5];
  const float* be  = (const float*)d_in[6];
  const float* ow  = (const float*)d_in[7];
  const float* ob  = (const float*)d_in[8];
  float* out = (float*)d_out;

  const int B = in_sizes[0] / TST;      // 16384
  const int grid = B / 16;              // 1024 blocks (512 thr) = 2 blocks/CU
  hipLaunchKernelGGL(rnn_kernel, dim3(grid), dim3(512), 0, stream,
                     x, ew, eb, uw, ub, g, be, ow, ob, out);
}

// Round 5
// 375.349 us; speedup vs baseline: 1.1780x; 1.1780x over previous
//
#include <hip/hip_runtime.h>
#include <hip/hip_fp16.h>
#include <math.h>

typedef _Float16 f16;
typedef _Float16 f16x8 __attribute__((ext_vector_type(8)));
typedef float f32x4 __attribute__((ext_vector_type(4)));
typedef unsigned char u8;

#define HDIM 256
#define TST 128
#define OUTD 10
#define S2LE 2.8853900817779268f   // 2*log2(e)

// 4 waves/block (256 thr). Wave w owns hidden rows [w*64, w*64+64) for ALL 32
// batch cols of the block (2 col-groups of 16). Grid = 512 = exactly 2
// blocks/CU resident -> ONE residency round.
// Bias-in-MFMA: chunk c=8 has A8[n][s] = D1[s][n] (s<10) / rsg[n] (s==10),
// B8[s] = one-hot(xv)*(1/rs_prev) + (s==10)*(-mu_prev). Then
// y_scaled = rs_prev * acc  (exactly R3/R4's verified algebra, re-folded).
__global__ __launch_bounds__(256, 2) void rnn_kernel(
    const float* __restrict__ x,
    const float* __restrict__ embed_w,
    const float* __restrict__ embed_b,
    const float* __restrict__ update_w,
    const float* __restrict__ update_b,
    const float* __restrict__ gamma,
    const float* __restrict__ beta,
    const float* __restrict__ out_w,
    const float* __restrict__ out_b,
    float* __restrict__ out)
{
  __shared__ __align__(16) f16   sFR[2][2][8][64][8]; // 32 KB frag dbuf; overlays: T0 (init), sOut (epi)
  __shared__ __align__(16) float sD1[10 * 260];       // 10.4 KB; overlay epi: sOW
  __shared__ __align__(16) float sBW[HDIM];
  __shared__ __align__(16) float sRSg[HDIM];
  __shared__ __align__(16) float sST[2][32][12];      // [p][col][2w]=s1,[2w+1]=s2; 48B rows
  __shared__ float sOB[16];
  __shared__ u8    sXb[TST][32];

  const int tid = threadIdx.x;
  const int w  = tid >> 6;      // 0..3
  const int l  = tid & 63;
  const int q  = l >> 4;
  const int ml = l & 15;
  const int base = blockIdx.x * 32;
  const int nb = w * 64 + q * 4;

  float* T0 = (float*)&sFR[0][0][0][0][0];   // [256][10] init-only

  // ---------- P1 ----------
  {
    float ew = embed_w[tid], eb = embed_b[tid];
    #pragma unroll
    for (int xv = 0; xv < 10; xv++)
      T0[tid * 10 + xv] = tanhf((float)xv * ew + eb);
  }
  for (int idx = tid; idx < 32 * TST; idx += 256) {
    int col = idx >> 7, tt = idx & 127;
    sXb[tt][col] = (u8)(int)x[(size_t)(base + col) * TST + tt];
  }
  if (tid < 16) {
    float v = 0.f;
    if (tid < OUTD) {
      v = out_b[tid];
      const float* orow = out_w + tid * HDIM;
      for (int k = 0; k < HDIM; k += 4) {
        float4 wv = *(const float4*)(orow + k);
        float4 bv = *(const float4*)(beta + k);
        v = fmaf(wv.x, bv.x, fmaf(wv.y, bv.y, fmaf(wv.z, bv.z, fmaf(wv.w, bv.w, v))));
      }
    }
    sOB[tid] = v;
  }
  __syncthreads();

  // ---------- P2: per-n tables (n = tid) ----------
  {
    const int n = tid;
    const float* wrow = update_w + n * HDIM;
    float ty[10];
    #pragma unroll
    for (int xv = 0; xv < 10; xv++) ty[xv] = 0.f;
    float bw = 0.f, rsg = 0.f;
    for (int k = 0; k < HDIM; k += 4) {
      float4 wv4 = *(const float4*)(wrow + k);
      float4 b4  = *(const float4*)(beta + k);
      float4 g4  = *(const float4*)(gamma + k);
      bw  = fmaf(wv4.x, b4.x, fmaf(wv4.y, b4.y, fmaf(wv4.z, b4.z, fmaf(wv4.w, b4.w, bw))));
      rsg = fmaf(wv4.x, S2LE * g4.x, fmaf(wv4.y, S2LE * g4.y,
            fmaf(wv4.z, S2LE * g4.z, fmaf(wv4.w, S2LE * g4.w, rsg))));
      #pragma unroll
      for (int kk = 0; kk < 4; kk++) {
        float wv = ((const float*)&wv4)[kk];
        const float* t0r = T0 + (k + kk) * 10;    // uniform addr -> broadcast
        #pragma unroll
        for (int xv = 0; xv < 10; xv++) ty[xv] = fmaf(wv, t0r[xv], ty[xv]);
      }
    }
    float ubn = update_b[n];
    sBW[n]  = S2LE * bw;
    sRSg[n] = rsg;
    #pragma unroll
    for (int xv = 0; xv < 10; xv++)
      sD1[xv * 260 + n] = S2LE * (ty[xv] + ubn + bw);
  }
  __syncthreads();

  // ---------- W fragments: chunks 0..7 (128 regs) + chunk 8 (16 regs) ----------
  f16x8 wf[4][8];
  #pragma unroll
  for (int c = 0; c < 8; c++) {
    const int k0 = c * 32 + q * 4;
    float4 g0 = *(const float4*)(gamma + k0);
    float4 g1 = *(const float4*)(gamma + k0 + 16);
    #pragma unroll
    for (int nt = 0; nt < 4; nt++) {
      const float* wrow = update_w + (w * 64 + nt * 16 + ml) * HDIM;
      float4 a0 = *(const float4*)(wrow + k0);
      float4 a1 = *(const float4*)(wrow + k0 + 16);
      f16x8 f;
      f[0]=(f16)(S2LE*g0.x*a0.x); f[1]=(f16)(S2LE*g0.y*a0.y);
      f[2]=(f16)(S2LE*g0.z*a0.z); f[3]=(f16)(S2LE*g0.w*a0.w);
      f[4]=(f16)(S2LE*g1.x*a1.x); f[5]=(f16)(S2LE*g1.y*a1.y);
      f[6]=(f16)(S2LE*g1.z*a1.z); f[7]=(f16)(S2LE*g1.w*a1.w);
      wf[nt][c] = f;
    }
  }
  f16x8 wf8[4];
  #pragma unroll
  for (int nt = 0; nt < 4; nt++) {
    const int n = w * 64 + nt * 16 + ml;
    f16x8 f;
    #pragma unroll
    for (int j = 0; j < 8; j++) {
      const int s = q * 4 + (j & 3) + 16 * (j >> 2);
      float v = (s < 10) ? sD1[s * 260 + n] : ((s == 10) ? sRSg[n] : 0.f);
      f[j] = (f16)v;
    }
    wf8[nt] = f;
  }

  // ---------- prologue t=0: y0 = D1[xv0] - BW ----------
  f32x4 acc[2][4];
  {
    float p1g[2], p2g[2];
    #pragma unroll
    for (int g = 0; g < 2; g++) {
      const int xv0 = (int)sXb[0][g * 16 + ml];
      const float* dp = sD1 + xv0 * 260;
      float p1 = 0.f, p2 = 0.f;
      #pragma unroll
      for (int nt = 0; nt < 4; nt++) {
        f32x4 dd = *(const f32x4*)(dp + nb + nt * 16);
        f32x4 bw = *(const f32x4*)(sBW + nb + nt * 16);
        #pragma unroll
        for (int r = 0; r < 4; r++) {
          float y = dd[r] - bw[r];
          float e = __builtin_amdgcn_exp2f(y);
          float t = fmaf(-2.f, __builtin_amdgcn_rcpf(e + 1.f), 1.f);
          acc[g][nt][r] = t; p1 += t; p2 = fmaf(t, t, p2);
        }
      }
      p1g[g] = p1; p2g[g] = p2;
    }
    #pragma unroll
    for (int g = 0; g < 2; g++) {
      p1g[g] += __shfl_xor(p1g[g], 16, 64); p2g[g] += __shfl_xor(p2g[g], 16, 64);
      p1g[g] += __shfl_xor(p1g[g], 32, 64); p2g[g] += __shfl_xor(p2g[g], 32, 64);
    }
    #pragma unroll
    for (int g = 0; g < 2; g++) {
      #pragma unroll
      for (int cp = 0; cp < 2; cp++) {
        f16x8 af;
        #pragma unroll
        for (int j = 0; j < 8; j++) af[j] = (f16)acc[g][2 * cp + (j >> 2)][j & 3];
        *(f16x8*)&sFR[0][g][2 * w + cp][l][0] = af;
      }
    }
    if (l < 32) {
      int col = (l < 16) ? ml : (16 + ml);
      float2 v2 = (l < 16) ? make_float2(p1g[0], p2g[0]) : make_float2(p1g[1], p2g[1]);
      *(float2*)&sST[0][col][2 * w] = v2;
    }
    __syncthreads();
  }

  // ---------- main loop: 1 barrier/step ----------
  #pragma unroll 1
  for (int t = 1; t < TST; t++) {
    const int p = t & 1, pp = p ^ 1;
    // stats reads issue first (consumed after MFMA c0..7 issue)
    const float* st0 = &sST[pp][ml][0];
    const float* st1 = &sST[pp][16 + ml][0];
    f32x4 u0 = *(const f32x4*)(st0);
    f32x4 u1 = *(const f32x4*)(st0 + 4);
    f32x4 v0 = *(const f32x4*)(st1);
    f32x4 v1 = *(const f32x4*)(st1 + 4);
    const int xva = (int)sXb[t][ml];
    const int xvb = (int)sXb[t][16 + ml];

    const f16* fb0 = &sFR[pp][0][0][0][0];
    const f16* fb1 = &sFR[pp][1][0][0][0];
    f16x8 rA0 = *(const f16x8*)(fb0 + l * 8);
    f16x8 rA1 = *(const f16x8*)(fb1 + l * 8);
    f16x8 rB0, rB1;

    #pragma unroll
    for (int g = 0; g < 2; g++)
      #pragma unroll
      for (int nt = 0; nt < 4; nt++)
        acc[g][nt] = (f32x4){0.f, 0.f, 0.f, 0.f};

    __builtin_amdgcn_s_setprio(1);
#define DO_C(CC, C0, C1, N0, N1)                                                  \
    {                                                                             \
      if ((CC) < 7) {                                                             \
        N0 = *(const f16x8*)(fb0 + ((CC) + 1) * 512 + l * 8);                     \
        N1 = *(const f16x8*)(fb1 + ((CC) + 1) * 512 + l * 8);                     \
      }                                                                           \
      acc[0][0] = __builtin_amdgcn_mfma_f32_16x16x32_f16(wf[0][CC], C0, acc[0][0],0,0,0); \
      acc[0][1] = __builtin_amdgcn_mfma_f32_16x16x32_f16(wf[1][CC], C0, acc[0][1],0,0,0); \
      acc[0][2] = __builtin_amdgcn_mfma_f32_16x16x32_f16(wf[2][CC], C0, acc[0][2],0,0,0); \
      acc[0][3] = __builtin_amdgcn_mfma_f32_16x16x32_f16(wf[3][CC], C0, acc[0][3],0,0,0); \
      acc[1][0] = __builtin_amdgcn_mfma_f32_16x16x32_f16(wf[0][CC], C1, acc[1][0],0,0,0); \
      acc[1][1] = __builtin_amdgcn_mfma_f32_16x16x32_f16(wf[1][CC], C1, acc[1][1],0,0,0); \
      acc[1][2] = __builtin_amdgcn_mfma_f32_16x16x32_f16(wf[2][CC], C1, acc[1][2],0,0,0); \
      acc[1][3] = __builtin_amdgcn_mfma_f32_16x16x32_f16(wf[3][CC], C1, acc[1][3],0,0,0); \
    }
    DO_C(0, rA0, rA1, rB0, rB1)
    DO_C(1, rB0, rB1, rA0, rA1)
    DO_C(2, rA0, rA1, rB0, rB1)
    DO_C(3, rB0, rB1, rA0, rA1)
    DO_C(4, rA0, rA1, rB0, rB1)
    DO_C(5, rB0, rB1, rA0, rA1)
    DO_C(6, rA0, rA1, rB0, rB1)
    DO_C(7, rB0, rB1, rA0, rA1)
#undef DO_C
    // stats reduce (overlaps MFMA cluster above in issue order)
    float s1a = (u0[0] + u0[2]) + (u1[0] + u1[2]);
    float s2a = (u0[1] + u0[3]) + (u1[1] + u1[3]);
    float s1b = (v0[0] + v0[2]) + (v1[0] + v1[2]);
    float s2b = (v0[1] + v0[3]) + (v1[1] + v1[3]);
    float mua = s1a * (1.f / 256.f);
    float vea = fmaf(s2a, 1.f / 256.f, -mua * mua) + 1e-5f;
    float rsa = __frsqrt_rn(vea);
    float iva = __builtin_amdgcn_sqrtf(vea);
    float mub = s1b * (1.f / 256.f);
    float veb = fmaf(s2b, 1.f / 256.f, -mub * mub) + 1e-5f;
    float rsb = __frsqrt_rn(veb);
    float ivb = __builtin_amdgcn_sqrtf(veb);
    // B8 one-hot frags
    f16x8 b8a, b8b;
    #pragma unroll
    for (int j = 0; j < 8; j++) {
      const int s = q * 4 + (j & 3) + 16 * (j >> 2);
      float va = (s == xva) ? iva : ((s == 10) ? -mua : 0.f);
      float vb = (s == xvb) ? ivb : ((s == 10) ? -mub : 0.f);
      b8a[j] = (f16)va; b8b[j] = (f16)vb;
    }
    acc[0][0] = __builtin_amdgcn_mfma_f32_16x16x32_f16(wf8[0], b8a, acc[0][0],0,0,0);
    acc[0][1] = __builtin_amdgcn_mfma_f32_16x16x32_f16(wf8[1], b8a, acc[0][1],0,0,0);
    acc[0][2] = __builtin_amdgcn_mfma_f32_16x16x32_f16(wf8[2], b8a, acc[0][2],0,0,0);
    acc[0][3] = __builtin_amdgcn_mfma_f32_16x16x32_f16(wf8[3], b8a, acc[0][3],0,0,0);
    acc[1][0] = __builtin_amdgcn_mfma_f32_16x16x32_f16(wf8[0], b8b, acc[1][0],0,0,0);
    acc[1][1] = __builtin_amdgcn_mfma_f32_16x16x32_f16(wf8[1], b8b, acc[1][1],0,0,0);
    acc[1][2] = __builtin_amdgcn_mfma_f32_16x16x32_f16(wf8[2], b8b, acc[1][2],0,0,0);
    acc[1][3] = __builtin_amdgcn_mfma_f32_16x16x32_f16(wf8[3], b8b, acc[1][3],0,0,0);
    __builtin_amdgcn_s_setprio(0);

    // y = rs*acc ; tanh ; stats ; pack
    float p1g[2], p2g[2];
    #pragma unroll
    for (int g = 0; g < 2; g++) {
      const float rsg2 = (g == 0) ? rsa : rsb;
      float p1 = 0.f, p2 = 0.f;
      #pragma unroll
      for (int nt = 0; nt < 4; nt++) {
        #pragma unroll
        for (int r = 0; r < 4; r++) {
          float y = rsg2 * acc[g][nt][r];
          float e = __builtin_amdgcn_exp2f(y);
          float tv = fmaf(-2.f, __builtin_amdgcn_rcpf(e + 1.f), 1.f);
          acc[g][nt][r] = tv; p1 += tv; p2 = fmaf(tv, tv, p2);
        }
      }
      p1g[g] = p1; p2g[g] = p2;
    }
    #pragma unroll
    for (int g = 0; g < 2; g++) {
      #pragma unroll
      for (int cp = 0; cp < 2; cp++) {
        f16x8 af;
        #pragma unroll
        for (int j = 0; j < 8; j++) af[j] = (f16)acc[g][2 * cp + (j >> 2)][j & 3];
        *(f16x8*)&sFR[p][g][2 * w + cp][l][0] = af;
      }
    }
    #pragma unroll
    for (int g = 0; g < 2; g++) {
      p1g[g] += __shfl_xor(p1g[g], 16, 64); p2g[g] += __shfl_xor(p2g[g], 16, 64);
      p1g[g] += __shfl_xor(p1g[g], 32, 64); p2g[g] += __shfl_xor(p2g[g], 32, 64);
    }
    if (l < 32) {
      int col = (l < 16) ? ml : (16 + ml);
      float2 v2 = (l < 16) ? make_float2(p1g[0], p2g[0]) : make_float2(p1g[1], p2g[1]);
      *(float2*)&sST[p][col][2 * w] = v2;
    }
    __syncthreads();
  }

  // ---------- epilogue ----------
  {
    // final stats (written at t=127 -> p=1)
    const float* st0 = &sST[1][ml][0];
    const float* st1 = &sST[1][16 + ml][0];
    f32x4 u0 = *(const f32x4*)(st0);
    f32x4 u1 = *(const f32x4*)(st0 + 4);
    f32x4 v0 = *(const f32x4*)(st1);
    f32x4 v1 = *(const f32x4*)(st1 + 4);
    float s1a = (u0[0] + u0[2]) + (u1[0] + u1[2]);
    float s2a = (u0[1] + u0[3]) + (u1[1] + u1[3]);
    float s1b = (v0[0] + v0[2]) + (v1[0] + v1[2]);
    float s2b = (v0[1] + v0[3]) + (v1[1] + v1[3]);
    float rs_f[2], nrsmu[2];
    {
      float mua = s1a * (1.f / 256.f);
      float vea = fmaf(s2a, 1.f / 256.f, -mua * mua) + 1e-5f;
      rs_f[0] = __frsqrt_rn(vea); nrsmu[0] = -rs_f[0] * mua;
      float mub = s1b * (1.f / 256.f);
      float veb = fmaf(s2b, 1.f / 256.f, -mub * mub) + 1e-5f;
      rs_f[1] = __frsqrt_rn(veb); nrsmu[1] = -rs_f[1] * mub;
    }
    // sOW over sD1
    f16* sOW = (f16*)sD1;
    for (int idx = tid; idx < 512; idx += 256) {
      int c = idx >> 6, l2 = idx & 63, q2 = l2 >> 4, o = l2 & 15;
      int k0 = c * 32 + q2 * 4;
      f16x8 f;
      #pragma unroll
      for (int j = 0; j < 8; j++) f[j] = (f16)0.f;
      if (o < OUTD) {
        const float* orow = out_w + o * HDIM;
        float4 a0 = *(const float4*)(orow + k0);
        float4 a1 = *(const float4*)(orow + k0 + 16);
        float4 g0 = *(const float4*)(gamma + k0);
        float4 g1 = *(const float4*)(gamma + k0 + 16);
        f[0]=(f16)(g0.x*a0.x); f[1]=(f16)(g0.y*a0.y); f[2]=(f16)(g0.z*a0.z); f[3]=(f16)(g0.w*a0.w);
        f[4]=(f16)(g1.x*a1.x); f[5]=(f16)(g1.y*a1.y); f[6]=(f16)(g1.z*a1.z); f[7]=(f16)(g1.w*a1.w);
      }
      *(f16x8*)(sOW + idx * 8) = f;
    }
    __syncthreads();
    float* sOut = (float*)&sFR[1][0][0][0][0];  // [2][4][16][16] floats, 8 KB
    #pragma unroll
    for (int g = 0; g < 2; g++) {
      f32x4 aO = {0.f, 0.f, 0.f, 0.f};
      #pragma unroll
      for (int cp = 0; cp < 2; cp++) {
        f16x8 af;
        #pragma unroll
        for (int j = 0; j < 8; j++)
          af[j] = (f16)fmaf(rs_f[g], acc[g][2 * cp + (j >> 2)][j & 3], nrsmu[g]);
        f16x8 of = *(const f16x8*)(sOW + ((size_t)(2 * w + cp) * 64 + l) * 8);
        aO = __builtin_amdgcn_mfma_f32_16x16x32_f16(of, af, aO, 0, 0, 0);
      }
      #pragma unroll
      for (int r = 0; r < 4; r++)
        sOut[((g * 4 + w) * 16 + ml) * 16 + q * 4 + r] = aO[r];
    }
    __syncthreads();
    for (int idx = tid; idx < 32 * OUTD; idx += 256) {
      int m = idx / OUTD, o = idx - m * OUTD;
      int g = m >> 4, mm = m & 15;
      float s = 0.f;
      #pragma unroll
      for (int ww = 0; ww < 4; ww++) s += sOut[((g * 4 + ww) * 16 + mm) * 16 + o];
      out[(size_t)(base + m) * OUTD + o] = s + sOB[o];
    }
  }
}

extern "C" void kernel_launch(void* const* d_in, const int* in_sizes, int n_in,
                              void* d_out, int out_size, void* d_ws, size_t ws_size,
                              hipStream_t stream) {
  const float* x   = (const float*)d_in[0];
  const float* ew  = (const float*)d_in[1];
  const float* eb  = (const float*)d_in[2];
  const float* uw  = (const float*)d_in[3];
  const float* ub  = (const float*)d_in[4];
  const float* g   = (const float*)d_in[5];
  const float* be  = (const float*)d_in[6];
  const float* ow  = (const float*)d_in[7];
  const float* ob  = (const float*)d_in[8];
  float* out = (float*)d_out;

  const int B = in_sizes[0] / TST;      // 16384
  const int grid = B / 32;              // 512 blocks = 2/CU, ONE round
  hipLaunchKernelGGL(rnn_kernel, dim3(grid), dim3(256), 0, stream,
                     x, ew, eb, uw, ub, g, be, ow, ob, out);
}